// Round 1
// baseline (631.334 us; speedup 1.0000x reference)
//
#include <hip/hip_runtime.h>
#include <math.h>

#define NB 32
#define NS 8192
#define NC 64
#define NM 16
#define NL 4
#define NM2 32                 // 2*M (cos,sin interleaved)
#define NSB 16                 // superblocks for forward DFT reduction
#define POS_PER_SB (NS/NSB)    // 512
#define TILE 128

static __device__ __forceinline__ float gelu_exact(float v) {
    return 0.5f * v * (1.0f + erff(v * 0.7071067811865475f));
}

// Build trig table T[s][2m]=cos(2*pi*m*s/NS), T[s][2m+1]=sin(2*pi*m*s/NS)
__global__ void k_table(float* __restrict__ T) {
    int s = blockIdx.x * blockDim.x + threadIdx.x;
    if (s >= NS) return;
    const float w = 6.283185307179586f / (float)NS;
    float* row = T + (size_t)s * NM2;
    #pragma unroll
    for (int m = 0; m < NM; ++m) {
        int idx = (m * s) & (NS - 1);
        float a = w * (float)idx;
        float sv, cv;
        sincosf(a, &sv, &cv);
        row[2*m]   = cv;
        row[2*m+1] = sv;
    }
}

// h[b,s,c] = input[b,s,0]*enc_w[c] + enc_b[c]
__global__ void __launch_bounds__(256) k_enc(const float* __restrict__ x,
                                             const float* __restrict__ ew,
                                             const float* __restrict__ eb,
                                             float* __restrict__ h) {
    int p = blockIdx.x * blockDim.x + threadIdx.x;   // 0..NB*NS-1
    float xv = x[p];
    float4* out = (float4*)(h + (size_t)p * NC);
    #pragma unroll
    for (int q = 0; q < NC/4; ++q) {
        float4 w4 = ((const float4*)ew)[q];
        float4 b4 = ((const float4*)eb)[q];
        out[q] = make_float4(fmaf(xv, w4.x, b4.x), fmaf(xv, w4.y, b4.y),
                             fmaf(xv, w4.z, b4.z), fmaf(xv, w4.w, b4.w));
    }
}

// Forward partial DFT: partial[b][sb][c][k] = sum_{s in superblock} h[b,s,c]*T[s][k]
__global__ void __launch_bounds__(256) k_fwd(const float* __restrict__ h,
                                             const float* __restrict__ T,
                                             float* __restrict__ partial) {
    __shared__ float hs[TILE*NC];    // 32 KB
    __shared__ float ts[TILE*NM2];   // 16 KB
    int b = blockIdx.y, sb = blockIdx.x;
    int t = threadIdx.x;
    int c = t >> 2, g = t & 3;       // c 0..63, trig octet group g 0..3
    float acc[8];
    #pragma unroll
    for (int k = 0; k < 8; ++k) acc[k] = 0.f;

    for (int tile = 0; tile < POS_PER_SB/TILE; ++tile) {
        int sbase = sb * POS_PER_SB + tile * TILE;
        const float4* hg = (const float4*)(h + ((size_t)b*NS + sbase)*NC);
        float4* hs4 = (float4*)hs;
        #pragma unroll
        for (int k = 0; k < (TILE*NC/4)/256; ++k) hs4[t + 256*k] = hg[t + 256*k];
        const float4* tg = (const float4*)(T + (size_t)sbase*NM2);
        float4* ts4 = (float4*)ts;
        #pragma unroll
        for (int k = 0; k < (TILE*NM2/4)/256; ++k) ts4[t + 256*k] = tg[t + 256*k];
        __syncthreads();
        #pragma unroll 4
        for (int s = 0; s < TILE; ++s) {
            float hv = hs[s*NC + c];
            float4 t0 = ((const float4*)ts)[s*(NM2/4) + g*2];
            float4 t1 = ((const float4*)ts)[s*(NM2/4) + g*2 + 1];
            acc[0] = fmaf(hv, t0.x, acc[0]); acc[1] = fmaf(hv, t0.y, acc[1]);
            acc[2] = fmaf(hv, t0.z, acc[2]); acc[3] = fmaf(hv, t0.w, acc[3]);
            acc[4] = fmaf(hv, t1.x, acc[4]); acc[5] = fmaf(hv, t1.y, acc[5]);
            acc[6] = fmaf(hv, t1.z, acc[6]); acc[7] = fmaf(hv, t1.w, acc[7]);
        }
        __syncthreads();
    }
    float* p = partial + (((size_t)b*NSB + sb)*NC + c)*NM2 + (size_t)g*8;
    ((float4*)p)[0] = make_float4(acc[0], acc[1], acc[2], acc[3]);
    ((float4*)p)[1] = make_float4(acc[4], acc[5], acc[6], acc[7]);
}

// Reduce partials -> x_ft, apply complex R mixing, pre-scale for inverse transform.
// xf[c][2m] = sum_s h*cos (= Re x_ft), xf[c][2m+1] = sum_s h*sin (= -Im x_ft)
// y_re = sum_i xr*Rre + xs*Rim ;  y_im = sum_i xr*Rim - xs*Rre
// ys[o][2m] = (m==0 ? 1 : 2)/NS * y_re ; ys[o][2m+1] = (m==0 ? 0 : -2/NS * y_im)
__global__ void __launch_bounds__(256) k_mix(const float* __restrict__ partial,
                                             const float* __restrict__ Rre,
                                             const float* __restrict__ Rim,
                                             float* __restrict__ ys, int l) {
    __shared__ float xf[NC*NM2];   // 8 KB
    int b = blockIdx.x, t = threadIdx.x;
    #pragma unroll
    for (int e = 0; e < (NC*NM2)/256; ++e) {   // 8 entries/thread
        int idx = t + 256*e;
        float s = 0.f;
        #pragma unroll
        for (int sb = 0; sb < NSB; ++sb)
            s += partial[((size_t)b*NSB + sb)*(NC*NM2) + idx];
        xf[idx] = s;
    }
    __syncthreads();
    #pragma unroll
    for (int j = 0; j < (NC*NM)/256; ++j) {    // 4 (o,m) pairs/thread
        int p = t + 256*j;
        int o = p >> 4, m = p & 15;
        float yre = 0.f, yim = 0.f;
        #pragma unroll 8
        for (int i = 0; i < NC; ++i) {
            float xr = xf[i*NM2 + 2*m];
            float xs = xf[i*NM2 + 2*m + 1];
            size_t ridx = (((size_t)l*NC + i)*NC + o)*NM + m;
            float rr = Rre[ridx], ri = Rim[ridx];
            yre = fmaf(xr, rr, yre); yre = fmaf(xs, ri, yre);
            yim = fmaf(xr, ri, yim); yim = fmaf(-xs, rr, yim);
        }
        float* yo = ys + ((size_t)b*NC + o)*NM2;
        if (m == 0) { yo[0] = yre * (1.0f/NS); yo[1] = 0.f; }
        else        { yo[2*m] = yre * (2.0f/NS); yo[2*m+1] = -yim * (2.0f/NS); }
    }
}

// Fused: h[b,s,o] = gelu( (W[l] h[b,s,:])[o] + Wb[l][o] + dot(ys[b][o][:], T[s][:]) )
// In-place on h (each position read fully before written by its own thread).
__global__ void __launch_bounds__(256) k_spec(float* __restrict__ h,
                                              const float* __restrict__ T,
                                              const float* __restrict__ ys,
                                              const float* __restrict__ W,
                                              const float* __restrict__ Wb, int l) {
    int b = blockIdx.y;
    int s = blockIdx.x * 256 + threadIdx.x;
    float* hp = h + ((size_t)b*NS + s)*NC;
    float hin[NC];
    #pragma unroll
    for (int q = 0; q < NC/4; ++q) {
        float4 v = ((const float4*)hp)[q];
        hin[4*q] = v.x; hin[4*q+1] = v.y; hin[4*q+2] = v.z; hin[4*q+3] = v.w;
    }
    float tt[NM2];
    const float4* tg = (const float4*)(T + (size_t)s*NM2);
    #pragma unroll
    for (int q = 0; q < NM2/4; ++q) {
        float4 v = tg[q];
        tt[4*q] = v.x; tt[4*q+1] = v.y; tt[4*q+2] = v.z; tt[4*q+3] = v.w;
    }
    const float* Wl = W  + (size_t)l*NC*NC;   // wave-uniform reads -> s_load
    const float* bl = Wb + (size_t)l*NC;
    const float* yb = ys + (size_t)b*NC*NM2;
    #pragma unroll 1
    for (int o4 = 0; o4 < NC/4; ++o4) {
        float rv[4];
        #pragma unroll
        for (int j = 0; j < 4; ++j) {
            int o = o4*4 + j;
            float a = bl[o];
            #pragma unroll
            for (int i = 0; i < NC; ++i) a = fmaf(Wl[o*NC + i], hin[i], a);
            float sp = 0.f;
            #pragma unroll
            for (int k = 0; k < NM2; ++k) sp = fmaf(yb[o*NM2 + k], tt[k], sp);
            rv[j] = gelu_exact(a + sp);
        }
        ((float4*)hp)[o4] = make_float4(rv[0], rv[1], rv[2], rv[3]);
    }
}

// Fused decoder: out[p] = d2_b + sum_o d2_w[o]*gelu(d1_b[o] + sum_c d1_w[o,c]*h[p,c])
__global__ void __launch_bounds__(256) k_dec(const float* __restrict__ h,
                                             const float* __restrict__ d1w,
                                             const float* __restrict__ d1b,
                                             const float* __restrict__ d2w,
                                             const float* __restrict__ d2b,
                                             float* __restrict__ out) {
    int p = blockIdx.x * 256 + threadIdx.x;
    const float* hp = h + (size_t)p * NC;
    float hin[NC];
    #pragma unroll
    for (int q = 0; q < NC/4; ++q) {
        float4 v = ((const float4*)hp)[q];
        hin[4*q] = v.x; hin[4*q+1] = v.y; hin[4*q+2] = v.z; hin[4*q+3] = v.w;
    }
    float acc = d2b[0];
    #pragma unroll 1
    for (int o = 0; o < NC; ++o) {
        float a = d1b[o];
        #pragma unroll
        for (int i = 0; i < NC; ++i) a = fmaf(d1w[o*NC + i], hin[i], a);
        acc = fmaf(gelu_exact(a), d2w[o], acc);
    }
    out[p] = acc;
}

extern "C" void kernel_launch(void* const* d_in, const int* in_sizes, int n_in,
                              void* d_out, int out_size, void* d_ws, size_t ws_size,
                              hipStream_t stream) {
    const float* input = (const float*)d_in[0];
    const float* enc_w = (const float*)d_in[1];
    const float* enc_b = (const float*)d_in[2];
    const float* R_re  = (const float*)d_in[3];
    const float* R_im  = (const float*)d_in[4];
    const float* Wl_w  = (const float*)d_in[5];
    const float* Wl_b  = (const float*)d_in[6];
    const float* d1_w  = (const float*)d_in[7];
    const float* d1_b  = (const float*)d_in[8];
    const float* d2_w  = (const float*)d_in[9];
    const float* d2_b  = (const float*)d_in[10];
    float* out = (float*)d_out;

    float* ws  = (float*)d_ws;
    float* h   = ws;                               // NB*NS*NC      = 16.78M floats
    float* T   = h  + (size_t)NB*NS*NC;            // NS*NM2        = 262144
    float* par = T  + (size_t)NS*NM2;              // NB*NSB*NC*NM2 = 1.05M
    float* ys  = par + (size_t)NB*NSB*NC*NM2;      // NB*NC*NM2     = 65536

    hipLaunchKernelGGL(k_table, dim3(NS/256), dim3(256), 0, stream, T);
    hipLaunchKernelGGL(k_enc, dim3((NB*NS)/256), dim3(256), 0, stream,
                       input, enc_w, enc_b, h);
    for (int l = 0; l < NL; ++l) {
        hipLaunchKernelGGL(k_fwd, dim3(NSB, NB), dim3(256), 0, stream, h, T, par);
        hipLaunchKernelGGL(k_mix, dim3(NB), dim3(256), 0, stream,
                           par, R_re, R_im, ys, l);
        hipLaunchKernelGGL(k_spec, dim3(NS/256, NB), dim3(256), 0, stream,
                           h, T, ys, Wl_w, Wl_b, l);
    }
    hipLaunchKernelGGL(k_dec, dim3((NB*NS)/256), dim3(256), 0, stream,
                       h, d1_w, d1_b, d2_w, d2_b, out);
}

// Round 3
// 596.983 us; speedup vs baseline: 1.0575x; 1.0575x over previous
//
#include <hip/hip_runtime.h>
#include <math.h>

#define NB 32
#define NS 8192
#define NC 64
#define NM 16
#define NL 4
#define NM2 32                 // 2*M (cos,sin interleaved)
#define NSBF 32                // forward-DFT superblocks per batch

static __device__ __forceinline__ float gelu_exact(float v) {
    return 0.5f * v * (1.0f + erff(v * 0.7071067811865475f));
}

// Build trig table T[s][2m]=cos(2*pi*m*s/NS), T[s][2m+1]=sin(2*pi*m*s/NS)
__global__ void k_table(float* __restrict__ T) {
    int s = blockIdx.x * blockDim.x + threadIdx.x;
    if (s >= NS) return;
    const float w = 6.283185307179586f / (float)NS;
    float* row = T + (size_t)s * NM2;
    #pragma unroll
    for (int m = 0; m < NM; ++m) {
        int idx = (m * s) & (NS - 1);
        float a = w * (float)idx;
        float sv, cv;
        sincosf(a, &sv, &cv);
        row[2*m]   = cv;
        row[2*m+1] = sv;
    }
}

// Transpose Wl_w [L][o][i] -> Wt [L][i][o]; d1_w [o][i] -> d1t [i][o]
__global__ void k_prep(const float* __restrict__ Ww, const float* __restrict__ d1w,
                       float* __restrict__ Wt, float* __restrict__ d1t) {
    int idx = blockIdx.x * 256 + threadIdx.x;
    if (idx < NL*NC*NC) {
        int l = idx / (NC*NC), r = idx % (NC*NC);
        int i = r / NC, o = r % NC;
        Wt[idx] = Ww[(size_t)l*NC*NC + (size_t)o*NC + i];
    } else if (idx < NL*NC*NC + NC*NC) {
        int r = idx - NL*NC*NC;
        int i = r / NC, o = r % NC;
        d1t[r] = d1w[(size_t)o*NC + i];
    }
}

// h[b,s,c] = input[b,s,0]*enc_w[c] + enc_b[c]
__global__ void __launch_bounds__(256) k_enc(const float* __restrict__ x,
                                             const float* __restrict__ ew,
                                             const float* __restrict__ eb,
                                             float* __restrict__ h) {
    int p = blockIdx.x * blockDim.x + threadIdx.x;   // 0..NB*NS-1
    float xv = x[p];
    float4* out = (float4*)(h + (size_t)p * NC);
    #pragma unroll
    for (int q = 0; q < NC/4; ++q) {
        float4 w4 = ((const float4*)ew)[q];
        float4 b4 = ((const float4*)eb)[q];
        out[q] = make_float4(fmaf(xv, w4.x, b4.x), fmaf(xv, w4.y, b4.y),
                             fmaf(xv, w4.z, b4.z), fmaf(xv, w4.w, b4.w));
    }
}

// Forward partial DFT. Wave = 64 channel lanes sharing one position at a time;
// trig row is wave-uniform (readfirstlane -> s_load). 4 waves/block reduced in LDS.
// partial[b][sb][c][k] = sum_{s in superblock sb} h[b,s,c]*T[s][k]
__global__ void __launch_bounds__(256) k_fwd(const float* __restrict__ h,
                                             const float* __restrict__ T,
                                             float* __restrict__ partial) {
    __shared__ float red[4 * NC * NM2];   // 32 KB
    int b = blockIdx.y, sb = blockIdx.x;
    int t = threadIdx.x;
    int w = t >> 6, lane = t & 63;        // lane = channel c
    const int PPW = NS / NSBF / 4;        // 64 positions per wave
    float acc[NM2];
    #pragma unroll
    for (int k = 0; k < NM2; ++k) acc[k] = 0.f;
    int s0 = sb * (NS / NSBF) + w * PPW;
    const float* hp = h + ((size_t)b*NS + s0)*NC + lane;
    #pragma unroll 2
    for (int it = 0; it < PPW; ++it) {
        float hv = hp[(size_t)it * NC];
        int su = __builtin_amdgcn_readfirstlane(s0 + it);
        const float* trow = T + (size_t)su * NM2;
        #pragma unroll
        for (int k = 0; k < NM2; ++k)
            acc[k] = fmaf(hv, trow[k], acc[k]);
    }
    #pragma unroll
    for (int k = 0; k < NM2; ++k) red[(w*NC + lane)*NM2 + k] = acc[k];
    __syncthreads();
    float* pout = partial + ((size_t)b*NSBF + sb) * (NC*NM2);
    #pragma unroll
    for (int e = 0; e < (NC*NM2)/256; ++e) {
        int idx = t + 256*e;              // idx = c*32 + k
        pout[idx] = red[idx] + red[idx + NC*NM2] + red[idx + 2*NC*NM2]
                  + red[idx + 3*NC*NM2];
    }
}

// Reduce partials -> x_ft, apply complex R mixing, pre-scale for inverse transform.
// Writes TRANSPOSED yst[b][k][o] so k_spec reads o-contiguous (uniform s_loads).
__global__ void __launch_bounds__(256) k_mix(const float* __restrict__ partial,
                                             const float* __restrict__ Rre,
                                             const float* __restrict__ Rim,
                                             float* __restrict__ yst, int l) {
    __shared__ float xf[NC*NM2];   // 8 KB
    int b = blockIdx.x, t = threadIdx.x;
    #pragma unroll
    for (int e = 0; e < (NC*NM2)/256; ++e) {
        int idx = t + 256*e;
        float s = 0.f;
        #pragma unroll 8
        for (int sb = 0; sb < NSBF; ++sb)
            s += partial[((size_t)b*NSBF + sb)*(NC*NM2) + idx];
        xf[idx] = s;
    }
    __syncthreads();
    #pragma unroll
    for (int j = 0; j < (NC*NM)/256; ++j) {    // 4 (o,m) pairs/thread
        int p = t + 256*j;
        int o = p >> 4, m = p & 15;
        float yre = 0.f, yim = 0.f;
        #pragma unroll 8
        for (int i = 0; i < NC; ++i) {
            float xr = xf[i*NM2 + 2*m];
            float xs = xf[i*NM2 + 2*m + 1];
            size_t ridx = (((size_t)l*NC + i)*NC + o)*NM + m;
            float rr = Rre[ridx], ri = Rim[ridx];
            yre = fmaf(xr, rr, yre); yre = fmaf(xs, ri, yre);
            yim = fmaf(xr, ri, yim); yim = fmaf(-xs, rr, yim);
        }
        float* yb = yst + (size_t)b*NM2*NC;
        if (m == 0) { yb[o] = yre * (1.0f/NS); yb[NC + o] = 0.f; }
        else {
            yb[(size_t)(2*m)*NC + o]   = yre * (2.0f/NS);
            yb[(size_t)(2*m+1)*NC + o] = -yim * (2.0f/NS);
        }
    }
}

// Fused spectral + Wl + GELU, in-place on h. One thread = one position.
// acc[64] output accumulators; weights i-outer/o-inner from transposed
// arrays -> wave-uniform scalar loads. All hp loads precede all stores.
__global__ void __launch_bounds__(256) k_spec(float* __restrict__ h,
                                              const float* __restrict__ T,
                                              const float* __restrict__ yst,
                                              const float* __restrict__ Wt,
                                              const float* __restrict__ Wb, int l) {
    int b = blockIdx.y;
    int s = blockIdx.x * 256 + threadIdx.x;
    float* hp = h + ((size_t)b*NS + s)*NC;

    const float* Wl = Wt + (size_t)l*NC*NC;    // [i][o]
    const float* bl = Wb + (size_t)l*NC;
    const float* yb = yst + (size_t)b*NM2*NC;  // [k][o]

    float acc[NC];
    #pragma unroll
    for (int o = 0; o < NC; ++o) acc[o] = bl[o];

    // spectral part: acc[o] += sum_k tt[k] * yst[k][o]
    {
        float tt[NM2];
        const float4* tg = (const float4*)(T + (size_t)s*NM2);
        #pragma unroll
        for (int q = 0; q < NM2/4; ++q) {
            float4 v = tg[q];
            tt[4*q] = v.x; tt[4*q+1] = v.y; tt[4*q+2] = v.z; tt[4*q+3] = v.w;
        }
        #pragma unroll 1
        for (int k4 = 0; k4 < NM2; k4 += 4) {
            #pragma unroll
            for (int kk = 0; kk < 4; ++kk) {
                float tv = tt[k4+kk];
                const float* yr = yb + (size_t)(k4+kk)*NC;
                #pragma unroll
                for (int o = 0; o < NC; ++o) acc[o] = fmaf(tv, yr[o], acc[o]);
            }
        }
    }

    // dense part: acc[o] += sum_i h[i] * Wt[i][o]
    #pragma unroll 1
    for (int i8 = 0; i8 < NC; i8 += 8) {
        float4 v0 = ((const float4*)(hp + i8))[0];
        float4 v1 = ((const float4*)(hp + i8))[1];
        float hin[8] = {v0.x, v0.y, v0.z, v0.w, v1.x, v1.y, v1.z, v1.w};
        #pragma unroll
        for (int di = 0; di < 8; ++di) {
            float hv = hin[di];
            const float* wr = Wl + (size_t)(i8+di)*NC;
            #pragma unroll
            for (int o = 0; o < NC; ++o) acc[o] = fmaf(hv, wr[o], acc[o]);
        }
    }

    #pragma unroll
    for (int o4 = 0; o4 < NC/4; ++o4) {
        float4 r;
        r.x = gelu_exact(acc[o4*4+0]);
        r.y = gelu_exact(acc[o4*4+1]);
        r.z = gelu_exact(acc[o4*4+2]);
        r.w = gelu_exact(acc[o4*4+3]);
        ((float4*)hp)[o4] = r;
    }
}

// Fused decoder: out[p] = d2_b + sum_o d2_w[o]*gelu(d1_b[o] + sum_i d1t[i][o]*h[p,i])
__global__ void __launch_bounds__(256) k_dec(const float* __restrict__ h,
                                             const float* __restrict__ d1t,
                                             const float* __restrict__ d1b,
                                             const float* __restrict__ d2w,
                                             const float* __restrict__ d2b,
                                             float* __restrict__ out) {
    int p = blockIdx.x * 256 + threadIdx.x;
    const float* hp = h + (size_t)p * NC;
    float acc[NC];
    #pragma unroll
    for (int o = 0; o < NC; ++o) acc[o] = d1b[o];
    #pragma unroll 1
    for (int i8 = 0; i8 < NC; i8 += 8) {
        float4 v0 = ((const float4*)(hp + i8))[0];
        float4 v1 = ((const float4*)(hp + i8))[1];
        float hin[8] = {v0.x, v0.y, v0.z, v0.w, v1.x, v1.y, v1.z, v1.w};
        #pragma unroll
        for (int di = 0; di < 8; ++di) {
            float hv = hin[di];
            const float* wr = d1t + (size_t)(i8+di)*NC;
            #pragma unroll
            for (int o = 0; o < NC; ++o) acc[o] = fmaf(hv, wr[o], acc[o]);
        }
    }
    float res = d2b[0];
    #pragma unroll
    for (int o = 0; o < NC; ++o) res = fmaf(gelu_exact(acc[o]), d2w[o], res);
    out[p] = res;
}

extern "C" void kernel_launch(void* const* d_in, const int* in_sizes, int n_in,
                              void* d_out, int out_size, void* d_ws, size_t ws_size,
                              hipStream_t stream) {
    const float* input = (const float*)d_in[0];
    const float* enc_w = (const float*)d_in[1];
    const float* enc_b = (const float*)d_in[2];
    const float* R_re  = (const float*)d_in[3];
    const float* R_im  = (const float*)d_in[4];
    const float* Wl_w  = (const float*)d_in[5];
    const float* Wl_b  = (const float*)d_in[6];
    const float* d1_w  = (const float*)d_in[7];
    const float* d1_b  = (const float*)d_in[8];
    const float* d2_w  = (const float*)d_in[9];
    const float* d2_b  = (const float*)d_in[10];
    float* out = (float*)d_out;

    float* ws  = (float*)d_ws;
    float* h   = ws;                               // 16.78M floats
    float* T   = h   + (size_t)NB*NS*NC;           // 262144
    float* par = T   + (size_t)NS*NM2;             // NB*NSBF*NC*NM2 = 2.10M
    float* yst = par + (size_t)NB*NSBF*NC*NM2;     // NB*NM2*NC = 65536
    float* Wt  = yst + (size_t)NB*NM2*NC;          // NL*NC*NC = 16384
    float* d1t = Wt  + (size_t)NL*NC*NC;           // NC*NC = 4096

    hipLaunchKernelGGL(k_table, dim3(NS/256), dim3(256), 0, stream, T);
    hipLaunchKernelGGL(k_prep, dim3((NL*NC*NC + NC*NC + 255)/256), dim3(256), 0,
                       stream, Wl_w, d1_w, Wt, d1t);
    hipLaunchKernelGGL(k_enc, dim3((NB*NS)/256), dim3(256), 0, stream,
                       input, enc_w, enc_b, h);
    for (int l = 0; l < NL; ++l) {
        hipLaunchKernelGGL(k_fwd, dim3(NSBF, NB), dim3(256), 0, stream, h, T, par);
        hipLaunchKernelGGL(k_mix, dim3(NB), dim3(256), 0, stream,
                           par, R_re, R_im, yst, l);
        hipLaunchKernelGGL(k_spec, dim3(NS/256, NB), dim3(256), 0, stream,
                           h, T, yst, Wt, Wl_b, l);
    }
    hipLaunchKernelGGL(k_dec, dim3((NB*NS)/256), dim3(256), 0, stream,
                       h, d1t, d1_b, d2_w, d2_b, out);
}